// Round 15
// baseline (1146.616 us; speedup 1.0000x reference)
//
#include <hip/hip_runtime.h>
#include <hip/hip_bf16.h>
#include <hip/hip_fp16.h>
#include <math.h>

#define NN 100000
#define NE 3200000
#define NF 256
#define NH 128
#define NC 40
#define BN_EPS 1e-5f
#define NB 98  // ceil(NN/1024)

typedef __attribute__((ext_vector_type(8))) short bf16x8;
typedef __attribute__((ext_vector_type(4))) float f32x4;

__device__ __forceinline__ float2 bf2_unpack(unsigned int v) {
    return make_float2(__uint_as_float(v << 16), __uint_as_float(v & 0xffff0000u));
}
__device__ __forceinline__ unsigned int pack2bf(float lo, float hi) {
    unsigned int a = (unsigned int)__hip_bfloat16_raw(__float2bfloat16(lo)).x;
    unsigned int b = (unsigned int)__hip_bfloat16_raw(__float2bfloat16(hi)).x;
    return a | (b << 16);
}
__device__ __forceinline__ float4 affine4(float4 v, float4 sc, float4 sh) {
    v.x = fmaf(v.x, sc.x, sh.x);
    v.y = fmaf(v.y, sc.y, sh.y);
    v.z = fmaf(v.z, sc.z, sh.z);
    v.w = fmaf(v.w, sc.w, sh.w);
    return v;
}

// ---------------- init: hist=0, sums=0 ----------------
__global__ __launch_bounds__(256) void k_init(unsigned long long* hist, float* sums) {
    int i = blockIdx.x * 256 + threadIdx.x;
    if (i < NN) hist[i] = 0ULL;
    if (i < 3 * 1024) sums[i] = 0.0f;
}

// ---------------- edge pass: ONE u64 packed atomic (count | 12.32 weight sum) ----------------
// pos[e] = slot_in_row (low16) | f16(w) (high16)  -> scatter skips the ew re-read.
__global__ __launch_bounds__(256) void k_edge(const int* __restrict__ ei, const float* __restrict__ ew,
                                              unsigned long long* __restrict__ hist,
                                              unsigned int* __restrict__ pos) {
    int e = blockIdx.x * 256 + threadIdx.x;
    if (e >= NE) return;
    int d = __builtin_nontemporal_load(&ei[NE + e]);
    float w = __builtin_nontemporal_load(&ew[e]);
    unsigned long long pack = (1ULL << 44) | (unsigned long long)(w * 4294967296.0f);
    unsigned long long old = atomicAdd(&hist[d], pack);
    unsigned int h16 = (unsigned int)__half_as_ushort(__float2half(w));
    __builtin_nontemporal_store((unsigned int)(old >> 44) | (h16 << 16), &pos[e]);
}

// ---------------- scan phase A: per-block partial count sums + dinv (parallel) ----------------
__global__ __launch_bounds__(256) void k_scanA(const unsigned long long* __restrict__ hist,
                                               int* __restrict__ partial,
                                               float* __restrict__ dinv) {
    __shared__ int ws[4];
    int t = threadIdx.x;
    int i0 = blockIdx.x * 1024 + t * 4;
    int s = 0;
#pragma unroll
    for (int j = 0; j < 4; j++) {
        int i = i0 + j;
        if (i < NN) {
            unsigned long long h = hist[i];
            s += (int)(h >> 44);
            float wsum = (float)(h & 0xFFFFFFFFFFFULL) * 2.3283064365386963e-10f;
            dinv[i] = rsqrtf(1.0f + wsum);
        }
    }
#pragma unroll
    for (int off = 32; off >= 1; off >>= 1) s += __shfl_xor(s, off);
    if ((t & 63) == 0) ws[t >> 6] = s;
    __syncthreads();
    if (t == 0) partial[blockIdx.x] = ws[0] + ws[1] + ws[2] + ws[3];
}

// ---------------- scan phase B: exclusive scan of NB partials (1 block) ----------------
__global__ void k_scanB(int* __restrict__ partial, int* __restrict__ rowptr) {
    __shared__ int buf[128];
    int t = threadIdx.x;
    buf[t] = (t < NB) ? partial[t] : 0;
    __syncthreads();
    if (t == 0) {
        int r = 0;
        for (int b = 0; b < NB; b++) { int v = buf[b]; buf[b] = r; r += v; }
        rowptr[NN] = r;
    }
    __syncthreads();
    if (t < NB) partial[t] = buf[t];
}

// ---------------- scan phase C: block-local exclusive scan + base -> rowptr ----------------
__global__ __launch_bounds__(256) void k_scanC(const unsigned long long* __restrict__ hist,
                                               const int* __restrict__ partial,
                                               int* __restrict__ rowptr) {
    __shared__ int wsum[4];
    int t = threadIdx.x;
    int lane = t & 63, wid = t >> 6;
    int i0 = blockIdx.x * 1024 + t * 4;
    int c[4];
#pragma unroll
    for (int j = 0; j < 4; j++) {
        int i = i0 + j;
        c[j] = (i < NN) ? (int)(hist[i] >> 44) : 0;
    }
    int v = c[0] + c[1] + c[2] + c[3];
    int x = v;
#pragma unroll
    for (int off = 1; off < 64; off <<= 1) {
        int y = __shfl_up(x, off);
        if (lane >= off) x += y;
    }
    if (lane == 63) wsum[wid] = x;
    __syncthreads();
    if (t == 0) {
        int r = 0;
#pragma unroll
        for (int w2 = 0; w2 < 4; w2++) { int s = wsum[w2]; wsum[w2] = r; r += s; }
    }
    __syncthreads();
    int start = partial[blockIdx.x] + wsum[wid] + x - v;
#pragma unroll
    for (int j = 0; j < 4; j++) {
        int i = i0 + j;
        if (i < NN) rowptr[i] = start;
        start += c[j];
    }
}

// ---------------- scatter edges into CSR (no atomics), packed u32 (src | f16norm<<17) ----------------
__global__ __launch_bounds__(256) void k_scatter(const int* __restrict__ ei,
                                                 const float* __restrict__ dinv,
                                                 const int* __restrict__ rowptr,
                                                 const unsigned int* __restrict__ pos,
                                                 unsigned int* __restrict__ cw) {
    int e = blockIdx.x * 256 + threadIdx.x;
    if (e >= NE) return;
    int s = __builtin_nontemporal_load(&ei[e]);
    int d = __builtin_nontemporal_load(&ei[NE + e]);
    unsigned int pw = __builtin_nontemporal_load(&pos[e]);
    float w = __half2float(__ushort_as_half((unsigned short)(pw >> 16)));
    float nv = dinv[s] * w * dinv[d];
    unsigned int h = (unsigned int)__half_as_ushort(__float2half(nv)) & 0x7fffu;
    unsigned int packed = (unsigned int)s | (h << 17);
    __builtin_nontemporal_store(packed, &cw[rowptr[d] + (int)(pw & 0xFFFFu)]);
}

// ---------------- shared GEMM body: out_bf16[NN,128] = H[NN,K] @ W[K,128] ----------------
// BN: per-k affine from LDS (scp/shp); normalized A written back to Hw ONLY for
// unclamped rows (clamped duplicate rows would race with the owning wave).
template <int K, bool BN>
__device__ __forceinline__ void gemm_body(unsigned int (*Bt)[20], const float* H, float* Hw,
                                          const float* scp, const float* shp, int ldh,
                                          const float* W, __hip_bfloat16* out, int blk, int t) {
    int wid = t >> 6, l = t & 63;
    int l15 = l & 15, lhi = l >> 4;
    int rowbase = blk * 128 + wid * 32;
    bool ok0 = (rowbase + l15) < NN;
    bool ok1 = (rowbase + 16 + l15) < NN;
    int ar0 = rowbase + l15;      if (ar0 >= NN) ar0 = NN - 1;
    int ar1 = rowbase + 16 + l15; if (ar1 >= NN) ar1 = NN - 1;

    f32x4 acc[2][8];
#pragma unroll
    for (int rt = 0; rt < 2; rt++)
#pragma unroll
        for (int ct = 0; ct < 8; ct++) acc[rt][ct] = (f32x4){0.f, 0.f, 0.f, 0.f};

    for (int kb = 0; kb < K / 32; kb++) {
        __syncthreads();
        for (int i = t; i < 2048; i += 256) {
            int c = i & 127, k2l = i >> 7;
            int k = kb * 32 + 2 * k2l;
            Bt[c][k2l] = pack2bf(W[(size_t)k * NH + c], W[(size_t)(k + 1) * NH + c]);
        }
        __syncthreads();
        int kk = kb * 32 + lhi * 8;
        const float4* a0p = (const float4*)&H[(size_t)ar0 * ldh + kk];
        const float4* a1p = (const float4*)&H[(size_t)ar1 * ldh + kk];
        float4 x0 = a0p[0], x1 = a0p[1];
        float4 y0 = a1p[0], y1 = a1p[1];
        if constexpr (BN) {
            float4 sc0 = *(const float4*)&scp[kk];
            float4 sc1 = *(const float4*)&scp[kk + 4];
            float4 sh0 = *(const float4*)&shp[kk];
            float4 sh1 = *(const float4*)&shp[kk + 4];
            x0 = affine4(x0, sc0, sh0); x1 = affine4(x1, sc1, sh1);
            y0 = affine4(y0, sc0, sh0); y1 = affine4(y1, sc1, sh1);
            if (ok0) {
                *(float4*)&Hw[(size_t)ar0 * ldh + kk] = x0;
                *(float4*)&Hw[(size_t)ar0 * ldh + kk + 4] = x1;
            }
            if (ok1) {
                *(float4*)&Hw[(size_t)ar1 * ldh + kk] = y0;
                *(float4*)&Hw[(size_t)ar1 * ldh + kk + 4] = y1;
            }
        }
        union { unsigned int u[4]; bf16x8 v; } af0, af1;
        af0.u[0] = pack2bf(x0.x, x0.y); af0.u[1] = pack2bf(x0.z, x0.w);
        af0.u[2] = pack2bf(x1.x, x1.y); af0.u[3] = pack2bf(x1.z, x1.w);
        af1.u[0] = pack2bf(y0.x, y0.y); af1.u[1] = pack2bf(y0.z, y0.w);
        af1.u[2] = pack2bf(y1.x, y1.y); af1.u[3] = pack2bf(y1.z, y1.w);
#pragma unroll
        for (int ct = 0; ct < 8; ct++) {
            bf16x8 b = *(const bf16x8*)&Bt[ct * 16 + l15][lhi * 4];
            acc[0][ct] = __builtin_amdgcn_mfma_f32_16x16x32_bf16(af0.v, b, acc[0][ct], 0, 0, 0);
            acc[1][ct] = __builtin_amdgcn_mfma_f32_16x16x32_bf16(af1.v, b, acc[1][ct], 0, 0, 0);
        }
    }
#pragma unroll
    for (int rt = 0; rt < 2; rt++)
#pragma unroll
        for (int ct = 0; ct < 8; ct++)
#pragma unroll
            for (int reg = 0; reg < 4; reg++) {
                int row = rowbase + rt * 16 + lhi * 4 + reg;
                if (row < NN)
                    out[(size_t)row * NH + ct * 16 + l15] = __float2bfloat16(acc[rt][ct][reg]);
            }
}

// ---------------- plain GEMM (layer 1) ----------------
__global__ __launch_bounds__(256) void k_gemm1(const float* __restrict__ H,
                                               const float* __restrict__ W,
                                               __hip_bfloat16* __restrict__ out) {
    __shared__ unsigned int Bt[128][20];
    gemm_body<NF, false>(Bt, H, nullptr, nullptr, nullptr, NF, W, out, (int)blockIdx.x, (int)threadIdx.x);
}

// ---------------- BN-fused GEMM for layers 2/3: scale/shift computed per block from raw sums ----------------
__global__ __launch_bounds__(256) void k_gemm_bn(const float* H, float* Hw,
                                                 const float* __restrict__ sums,
                                                 const float* __restrict__ g,
                                                 const float* __restrict__ beta,
                                                 const float* __restrict__ W,
                                                 __hip_bfloat16* __restrict__ out) {
    __shared__ unsigned int Bt[128][20];
    __shared__ __align__(16) float scL[128];
    __shared__ __align__(16) float shL[128];
    int t = threadIdx.x;
    if (t < 128) {
        float m = sums[t] * (1.0f / NN);
        float v = sums[NH + t] * (1.0f / NN) - m * m;
        float r = rsqrtf(v + BN_EPS);
        float sc = g[t] * r;
        scL[t] = sc;
        shL[t] = beta[t] - m * sc;
    }
    __syncthreads();
    gemm_body<NH, true>(Bt, H, Hw, scL, shL, 384, W, out, (int)blockIdx.x, (int)threadIdx.x);
}

// ---------------- CSR gather-aggregate (bf16 lin), full-row, 16-deep pipeline, 4 nodes/block ----------------
// Deliberately minimal: VGPR 12, no LDS, no barriers (R14 showed appended work costs 3x its savings).
__global__ __launch_bounds__(256) void k_agg(const unsigned int* __restrict__ linb,
                                             const float* __restrict__ dinv,
                                             const int* __restrict__ rowptr,
                                             const unsigned int* __restrict__ cw,
                                             const float* __restrict__ bias,
                                             float* __restrict__ outp, int do_relu) {
    int t = threadIdx.x;
    int node = blockIdx.x * 4 + (t >> 6);
    if (node >= NN) return;
    int ch = t & 63;
    int c = ch << 1;
    float di = dinv[node];
    float2 sv = bf2_unpack(linb[(size_t)node * 64 + ch]);
    float a0 = fmaf(sv.x, di * di, bias[c]);
    float a1 = fmaf(sv.y, di * di, bias[c + 1]);
    int beg = rowptr[node], end = rowptr[node + 1];
    int j = beg;
    for (; j + 16 <= end; j += 16) {
        unsigned int pk[16];
#pragma unroll
        for (int q = 0; q < 16; q++) pk[q] = cw[j + q];
        unsigned int v[16];
#pragma unroll
        for (int q = 0; q < 16; q++) v[q] = linb[(size_t)(pk[q] & 0x1FFFFu) * 64 + ch];
#pragma unroll
        for (int q = 0; q < 16; q++) {
            float w = __half2float(__ushort_as_half((unsigned short)(pk[q] >> 17)));
            float2 f = bf2_unpack(v[q]);
            a0 = fmaf(f.x, w, a0);
            a1 = fmaf(f.y, w, a1);
        }
    }
    for (; j + 4 <= end; j += 4) {
        unsigned int pk[4];
#pragma unroll
        for (int q = 0; q < 4; q++) pk[q] = cw[j + q];
        unsigned int v[4];
#pragma unroll
        for (int q = 0; q < 4; q++) v[q] = linb[(size_t)(pk[q] & 0x1FFFFu) * 64 + ch];
#pragma unroll
        for (int q = 0; q < 4; q++) {
            float w = __half2float(__ushort_as_half((unsigned short)(pk[q] >> 17)));
            float2 f = bf2_unpack(v[q]);
            a0 = fmaf(f.x, w, a0);
            a1 = fmaf(f.y, w, a1);
        }
    }
    for (; j < end; j++) {
        unsigned int pk = cw[j];
        unsigned int vv = linb[(size_t)(pk & 0x1FFFFu) * 64 + ch];
        float w = __half2float(__ushort_as_half((unsigned short)(pk >> 17)));
        float2 f = bf2_unpack(vv);
        a0 = fmaf(f.x, w, a0);
        a1 = fmaf(f.y, w, a1);
    }
    if (do_relu) { a0 = fmaxf(a0, 0.f); a1 = fmaxf(a1, 0.f); }
    *(float2*)&outp[(size_t)node * 384 + c] = make_float2(a0, a1);
}

// ---------------- BN stats, float4-vectorized: thread owns 4 channels, 8 rows/block-iter ----------------
__global__ __launch_bounds__(256) void k_stats(const float* __restrict__ pre, float* __restrict__ sums) {
    int t = threadIdx.x;
    int cq = t & 31;   // channels 4*cq .. 4*cq+3
    int h = t >> 5;    // row group 0..7
    float s0 = 0.f, s1 = 0.f, s2 = 0.f, s3 = 0.f;
    float q0 = 0.f, q1 = 0.f, q2 = 0.f, q3 = 0.f;
    for (int r = blockIdx.x * 8 + h; r < NN; r += gridDim.x * 8) {
        float4 v = *(const float4*)&pre[(size_t)r * 384 + cq * 4];
        s0 += v.x; s1 += v.y; s2 += v.z; s3 += v.w;
        q0 = fmaf(v.x, v.x, q0); q1 = fmaf(v.y, v.y, q1);
        q2 = fmaf(v.z, v.z, q2); q3 = fmaf(v.w, v.w, q3);
    }
    __shared__ float ls[256][8];
    ls[t][0] = s0; ls[t][1] = s1; ls[t][2] = s2; ls[t][3] = s3;
    ls[t][4] = q0; ls[t][5] = q1; ls[t][6] = q2; ls[t][7] = q3;
    __syncthreads();
    if (t < 32) {
        float S[8] = {0.f, 0.f, 0.f, 0.f, 0.f, 0.f, 0.f, 0.f};
#pragma unroll
        for (int hh = 0; hh < 8; hh++)
#pragma unroll
            for (int k = 0; k < 8; k++) S[k] += ls[hh * 32 + t][k];
#pragma unroll
        for (int k = 0; k < 4; k++) {
            atomicAdd(&sums[4 * t + k], S[k]);
            atomicAdd(&sums[NH + 4 * t + k], S[4 + k]);
        }
    }
}

// ---------------- final linear [NN,384]@[384,40] via MFMA + softmax; BN3 computed in-block ----------------
// Normalized x3 written back only for unclamped rows (clamped duplicates would race).
__global__ __launch_bounds__(256) void k_final(const float* __restrict__ embed, float* embedW,
                                               const float* __restrict__ sums3,
                                               const float* __restrict__ g3,
                                               const float* __restrict__ be3,
                                               const float* __restrict__ linW,
                                               const float* __restrict__ linb,
                                               float* __restrict__ logits, float* __restrict__ probs) {
    __shared__ unsigned int Wt[3 * 16 * 196];  // 37632 B
    __shared__ __align__(16) float scL[128];
    __shared__ __align__(16) float shL[128];
    int t = threadIdx.x;
    if (t < 128) {
        float m = sums3[t] * (1.0f / NN);
        float v = sums3[NH + t] * (1.0f / NN) - m * m;
        float r = rsqrtf(v + BN_EPS);
        float sc = g3[t] * r;
        scL[t] = sc;
        shL[t] = be3[t] - m * sc;
    }
    for (int i = t; i < 3 * 16 * 192; i += 256) {
        int ct = i / (16 * 192);
        int rem = i - ct * (16 * 192);
        int c = rem / 192, k2 = rem - c * 192;
        int col = ct * 16 + c;
        float lo = (col < NC) ? linW[(size_t)(2 * k2) * NC + col] : 0.f;
        float hi = (col < NC) ? linW[(size_t)(2 * k2 + 1) * NC + col] : 0.f;
        Wt[(ct * 16 + c) * 196 + k2] = pack2bf(lo, hi);
    }
    __syncthreads();

    int wid = t >> 6, l = t & 63;
    int rowbase = blockIdx.x * 64 + wid * 16;
    int l15 = l & 15, lhi = l >> 4;

    bool okA = (rowbase + l15) < NN;
    int arow = rowbase + l15;
    if (arow > NN - 1) arow = NN - 1;
    const float4* ap = (const float4*)&embed[(size_t)arow * 384 + lhi * 8];

    f32x4 acc0 = {0.f, 0.f, 0.f, 0.f};
    f32x4 acc1 = {0.f, 0.f, 0.f, 0.f};
    f32x4 acc2 = {0.f, 0.f, 0.f, 0.f};

    for (int kb = 0; kb < 12; kb++) {
        float4 a0 = ap[kb * 8];
        float4 a1 = ap[kb * 8 + 1];
        if (kb >= 8) {  // x3 columns: apply BN3 affine, write normalized back (owners only)
            int kk = kb * 32 + lhi * 8 - 256;
            float4 sc0 = *(const float4*)&scL[kk];
            float4 sc1 = *(const float4*)&scL[kk + 4];
            float4 sh0 = *(const float4*)&shL[kk];
            float4 sh1 = *(const float4*)&shL[kk + 4];
            a0 = affine4(a0, sc0, sh0);
            a1 = affine4(a1, sc1, sh1);
            if (okA) {
                *(float4*)&embedW[(size_t)arow * 384 + kb * 32 + lhi * 8] = a0;
                *(float4*)&embedW[(size_t)arow * 384 + kb * 32 + lhi * 8 + 4] = a1;
            }
        }
        union { unsigned int u[4]; bf16x8 v; } af;
        af.u[0] = pack2bf(a0.x, a0.y);
        af.u[1] = pack2bf(a0.z, a0.w);
        af.u[2] = pack2bf(a1.x, a1.y);
        af.u[3] = pack2bf(a1.z, a1.w);
        int wbase = kb * 16 + lhi * 4;
        bf16x8 b0 = *(const bf16x8*)&Wt[(0 * 16 + l15) * 196 + wbase];
        bf16x8 b1 = *(const bf16x8*)&Wt[(1 * 16 + l15) * 196 + wbase];
        bf16x8 b2 = *(const bf16x8*)&Wt[(2 * 16 + l15) * 196 + wbase];
        acc0 = __builtin_amdgcn_mfma_f32_16x16x32_bf16(af.v, b0, acc0, 0, 0, 0);
        acc1 = __builtin_amdgcn_mfma_f32_16x16x32_bf16(af.v, b1, acc1, 0, 0, 0);
        acc2 = __builtin_amdgcn_mfma_f32_16x16x32_bf16(af.v, b2, acc2, 0, 0, 0);
    }

    int col0 = 0 * 16 + l15, col1 = 1 * 16 + l15, col2 = 2 * 16 + l15;
    float lb0 = (col0 < NC) ? linb[col0] : 0.f;
    float lb1 = (col1 < NC) ? linb[col1] : 0.f;
    float lb2 = (col2 < NC) ? linb[col2] : 0.f;

#pragma unroll
    for (int reg = 0; reg < 4; reg++) {
        int row = rowbase + lhi * 4 + reg;
        float v0 = acc0[reg] + lb0;
        float v1 = acc1[reg] + lb1;
        float v2 = acc2[reg] + lb2;
        float m = fmaxf(v0, v1);
        if (col2 < NC) m = fmaxf(m, v2);
#pragma unroll
        for (int off = 1; off < 16; off <<= 1) m = fmaxf(m, __shfl_xor(m, off));
        float e0 = __expf(v0 - m);
        float e1 = __expf(v1 - m);
        float e2 = (col2 < NC) ? __expf(v2 - m) : 0.f;
        float s = e0 + e1 + e2;
#pragma unroll
        for (int off = 1; off < 16; off <<= 1) s += __shfl_xor(s, off);
        float inv = 1.0f / s;
        if (row < NN) {
            size_t base = (size_t)row * NC;
            logits[base + col0] = v0;
            probs[base + col0] = e0 * inv;
            logits[base + col1] = v1;
            probs[base + col1] = e1 * inv;
            if (col2 < NC) {
                logits[base + col2] = v2;
                probs[base + col2] = e2 * inv;
            }
        }
    }
}

extern "C" void kernel_launch(void* const* d_in, const int* in_sizes, int n_in,
                              void* d_out, int out_size, void* d_ws, size_t ws_size,
                              hipStream_t stream) {
    const float* x    = (const float*)d_in[0];
    const int*   ei   = (const int*)d_in[1];
    const float* ew   = (const float*)d_in[2];
    const float* W1   = (const float*)d_in[3];
    const float* b1   = (const float*)d_in[4];
    const float* g1   = (const float*)d_in[5];
    const float* be1  = (const float*)d_in[6];
    const float* W2   = (const float*)d_in[7];
    const float* b2   = (const float*)d_in[8];
    const float* g2   = (const float*)d_in[9];
    const float* be2  = (const float*)d_in[10];
    const float* W3   = (const float*)d_in[11];
    const float* b3   = (const float*)d_in[12];
    const float* g3   = (const float*)d_in[13];
    const float* be3  = (const float*)d_in[14];
    const float* linW = (const float*)d_in[15];
    const float* linb = (const float*)d_in[16];

    float* out    = (float*)d_out;
    float* logits = out;
    float* probs  = out + (size_t)NN * NC;
    float* embed  = out + (size_t)2 * NN * NC;

    char* ws = (char*)d_ws;
    size_t off = 0;
    auto alloc = [&](size_t bytes) -> char* {
        char* p = ws + off;
        off = (off + bytes + 255) & ~(size_t)255;
        return p;
    };
    float*              dinv    = (float*)alloc((size_t)NN * 4);
    unsigned long long* hist    = (unsigned long long*)alloc((size_t)NN * 8);
    int*                rowptr  = (int*)alloc((size_t)(NN + 1) * 4);
    int*                partial = (int*)alloc(128 * 4);
    unsigned int*       cw      = (unsigned int*)alloc((size_t)NE * 4);
    __hip_bfloat16*     lin     = (__hip_bfloat16*)alloc((size_t)NN * NH * 2);
    unsigned int*       pos     = (unsigned int*)alloc((size_t)NE * 4);
    float*              sums    = (float*)alloc(3 * 1024 * 4);
    (void)ws_size; (void)in_sizes; (void)n_in; (void)out_size;

    int gN = (NN + 255) / 256;
    int gE = (NE + 255) / 256;
    int gM = (NN + 127) / 128;
    int gA = (NN + 3) / 4;
    int gF = (NN + 63) / 64;

    k_init<<<gN, 256, 0, stream>>>(hist, sums);
    k_edge<<<gE, 256, 0, stream>>>(ei, ew, hist, pos);
    k_scanA<<<NB, 256, 0, stream>>>(hist, partial, dinv);
    k_scanB<<<1, 128, 0, stream>>>(partial, rowptr);
    k_scanC<<<NB, 256, 0, stream>>>(hist, partial, rowptr);
    k_scatter<<<gE, 256, 0, stream>>>(ei, dinv, rowptr, pos, cw);

    // layer 1
    k_gemm1<<<gM, 256, 0, stream>>>(x, W1, lin);
    k_agg<<<gA, 256, 0, stream>>>((const unsigned int*)lin, dinv, rowptr, cw, b1, embed + 0, 1);
    k_stats<<<1024, 256, 0, stream>>>(embed + 0, sums + 0);
    // layer 2: GEMM computes BN1 scale/shift in-block, normalizes x1, writes back + lin2
    k_gemm_bn<<<gM, 256, 0, stream>>>(embed + 0, embed + 0, sums + 0, g1, be1, W2, lin);
    k_agg<<<gA, 256, 0, stream>>>((const unsigned int*)lin, dinv, rowptr, cw, b2, embed + 128, 1);
    k_stats<<<1024, 256, 0, stream>>>(embed + 128, sums + 1024);
    // layer 3
    k_gemm_bn<<<gM, 256, 0, stream>>>(embed + 128, embed + 128, sums + 1024, g2, be2, W3, lin);
    k_agg<<<gA, 256, 0, stream>>>((const unsigned int*)lin, dinv, rowptr, cw, b3, embed + 256, 0);
    k_stats<<<1024, 256, 0, stream>>>(embed + 256, sums + 2048);
    // final linear + softmax; BN3 computed in-block, normalized x3 written back
    k_final<<<gF, 256, 0, stream>>>(embed, embed, sums + 2048, g3, be3, linW, linb, logits, probs);
}

// Round 16
// 946.558 us; speedup vs baseline: 1.2114x; 1.2114x over previous
//
#include <hip/hip_runtime.h>
#include <hip/hip_bf16.h>
#include <hip/hip_fp16.h>
#include <math.h>

#define NN 100000
#define NE 3200000
#define NF 256
#define NH 128
#define NC 40
#define BN_EPS 1e-5f
#define NB 98  // ceil(NN/1024)

typedef __attribute__((ext_vector_type(8))) short bf16x8;
typedef __attribute__((ext_vector_type(4))) float f32x4;

__device__ __forceinline__ float2 bf2_unpack(unsigned int v) {
    return make_float2(__uint_as_float(v << 16), __uint_as_float(v & 0xffff0000u));
}
__device__ __forceinline__ unsigned int pack2bf(float lo, float hi) {
    unsigned int a = (unsigned int)__hip_bfloat16_raw(__float2bfloat16(lo)).x;
    unsigned int b = (unsigned int)__hip_bfloat16_raw(__float2bfloat16(hi)).x;
    return a | (b << 16);
}
__device__ __forceinline__ float4 affine4(float4 v, float4 sc, float4 sh) {
    v.x = fmaf(v.x, sc.x, sh.x);
    v.y = fmaf(v.y, sc.y, sh.y);
    v.z = fmaf(v.z, sc.z, sh.z);
    v.w = fmaf(v.w, sc.w, sh.w);
    return v;
}

// ---------------- init: hist=0, sums=0 ----------------
__global__ __launch_bounds__(256) void k_init(unsigned long long* hist, float* sums) {
    int i = blockIdx.x * 256 + threadIdx.x;
    if (i < NN) hist[i] = 0ULL;
    if (i < 3 * 1024) sums[i] = 0.0f;
}

// ---------------- edge pass: ONE u64 packed atomic (count | 12.32 weight sum) ----------------
// pos[e] = slot_in_row (low16) | f16(w) (high16)  -> scatter skips the ew re-read.
__global__ __launch_bounds__(256) void k_edge(const int* __restrict__ ei, const float* __restrict__ ew,
                                              unsigned long long* __restrict__ hist,
                                              unsigned int* __restrict__ pos) {
    int e = blockIdx.x * 256 + threadIdx.x;
    if (e >= NE) return;
    int d = __builtin_nontemporal_load(&ei[NE + e]);
    float w = __builtin_nontemporal_load(&ew[e]);
    unsigned long long pack = (1ULL << 44) | (unsigned long long)(w * 4294967296.0f);
    unsigned long long old = atomicAdd(&hist[d], pack);
    unsigned int h16 = (unsigned int)__half_as_ushort(__float2half(w));
    __builtin_nontemporal_store((unsigned int)(old >> 44) | (h16 << 16), &pos[e]);
}

// ---------------- scan phase A: per-block partial count sums + dinv (parallel) ----------------
__global__ __launch_bounds__(256) void k_scanA(const unsigned long long* __restrict__ hist,
                                               int* __restrict__ partial,
                                               float* __restrict__ dinv) {
    __shared__ int ws[4];
    int t = threadIdx.x;
    int i0 = blockIdx.x * 1024 + t * 4;
    int s = 0;
#pragma unroll
    for (int j = 0; j < 4; j++) {
        int i = i0 + j;
        if (i < NN) {
            unsigned long long h = hist[i];
            s += (int)(h >> 44);
            float wsum = (float)(h & 0xFFFFFFFFFFFULL) * 2.3283064365386963e-10f;
            dinv[i] = rsqrtf(1.0f + wsum);
        }
    }
#pragma unroll
    for (int off = 32; off >= 1; off >>= 1) s += __shfl_xor(s, off);
    if ((t & 63) == 0) ws[t >> 6] = s;
    __syncthreads();
    if (t == 0) partial[blockIdx.x] = ws[0] + ws[1] + ws[2] + ws[3];
}

// ---------------- scan phase B: exclusive scan of NB partials (1 block) ----------------
__global__ void k_scanB(int* __restrict__ partial, int* __restrict__ rowptr) {
    __shared__ int buf[128];
    int t = threadIdx.x;
    buf[t] = (t < NB) ? partial[t] : 0;
    __syncthreads();
    if (t == 0) {
        int r = 0;
        for (int b = 0; b < NB; b++) { int v = buf[b]; buf[b] = r; r += v; }
        rowptr[NN] = r;
    }
    __syncthreads();
    if (t < NB) partial[t] = buf[t];
}

// ---------------- scan phase C: block-local exclusive scan + base -> rowptr ----------------
__global__ __launch_bounds__(256) void k_scanC(const unsigned long long* __restrict__ hist,
                                               const int* __restrict__ partial,
                                               int* __restrict__ rowptr) {
    __shared__ int wsum[4];
    int t = threadIdx.x;
    int lane = t & 63, wid = t >> 6;
    int i0 = blockIdx.x * 1024 + t * 4;
    int c[4];
#pragma unroll
    for (int j = 0; j < 4; j++) {
        int i = i0 + j;
        c[j] = (i < NN) ? (int)(hist[i] >> 44) : 0;
    }
    int v = c[0] + c[1] + c[2] + c[3];
    int x = v;
#pragma unroll
    for (int off = 1; off < 64; off <<= 1) {
        int y = __shfl_up(x, off);
        if (lane >= off) x += y;
    }
    if (lane == 63) wsum[wid] = x;
    __syncthreads();
    if (t == 0) {
        int r = 0;
#pragma unroll
        for (int w2 = 0; w2 < 4; w2++) { int s = wsum[w2]; wsum[w2] = r; r += s; }
    }
    __syncthreads();
    int start = partial[blockIdx.x] + wsum[wid] + x - v;
#pragma unroll
    for (int j = 0; j < 4; j++) {
        int i = i0 + j;
        if (i < NN) rowptr[i] = start;
        start += c[j];
    }
}

// ---------------- scatter edges into CSR (no atomics), packed u32 (src | f16norm<<17) ----------------
__global__ __launch_bounds__(256) void k_scatter(const int* __restrict__ ei,
                                                 const float* __restrict__ dinv,
                                                 const int* __restrict__ rowptr,
                                                 const unsigned int* __restrict__ pos,
                                                 unsigned int* __restrict__ cw) {
    int e = blockIdx.x * 256 + threadIdx.x;
    if (e >= NE) return;
    int s = __builtin_nontemporal_load(&ei[e]);
    int d = __builtin_nontemporal_load(&ei[NE + e]);
    unsigned int pw = __builtin_nontemporal_load(&pos[e]);
    float w = __half2float(__ushort_as_half((unsigned short)(pw >> 16)));
    float nv = dinv[s] * w * dinv[d];
    unsigned int h = (unsigned int)__half_as_ushort(__float2half(nv)) & 0x7fffu;
    unsigned int packed = (unsigned int)s | (h << 17);
    __builtin_nontemporal_store(packed, &cw[rowptr[d] + (int)(pw & 0xFFFFu)]);
}

// ---------------- shared GEMM body: out_bf16[NN,128] = H[NN,K] @ W[K,128] ----------------
// BN: per-k affine from LDS (scp/shp); normalized A written back to Hw ONLY for
// unclamped rows (clamped duplicate rows would race with the owning wave).
template <int K, bool BN>
__device__ __forceinline__ void gemm_body(unsigned int (*Bt)[20], const float* H, float* Hw,
                                          const float* scp, const float* shp, int ldh,
                                          const float* W, __hip_bfloat16* out, int blk, int t) {
    int wid = t >> 6, l = t & 63;
    int l15 = l & 15, lhi = l >> 4;
    int rowbase = blk * 128 + wid * 32;
    bool ok0 = (rowbase + l15) < NN;
    bool ok1 = (rowbase + 16 + l15) < NN;
    int ar0 = rowbase + l15;      if (ar0 >= NN) ar0 = NN - 1;
    int ar1 = rowbase + 16 + l15; if (ar1 >= NN) ar1 = NN - 1;

    f32x4 acc[2][8];
#pragma unroll
    for (int rt = 0; rt < 2; rt++)
#pragma unroll
        for (int ct = 0; ct < 8; ct++) acc[rt][ct] = (f32x4){0.f, 0.f, 0.f, 0.f};

    for (int kb = 0; kb < K / 32; kb++) {
        __syncthreads();
        for (int i = t; i < 2048; i += 256) {
            int c = i & 127, k2l = i >> 7;
            int k = kb * 32 + 2 * k2l;
            Bt[c][k2l] = pack2bf(W[(size_t)k * NH + c], W[(size_t)(k + 1) * NH + c]);
        }
        __syncthreads();
        int kk = kb * 32 + lhi * 8;
        const float4* a0p = (const float4*)&H[(size_t)ar0 * ldh + kk];
        const float4* a1p = (const float4*)&H[(size_t)ar1 * ldh + kk];
        float4 x0 = a0p[0], x1 = a0p[1];
        float4 y0 = a1p[0], y1 = a1p[1];
        if constexpr (BN) {
            float4 sc0 = *(const float4*)&scp[kk];
            float4 sc1 = *(const float4*)&scp[kk + 4];
            float4 sh0 = *(const float4*)&shp[kk];
            float4 sh1 = *(const float4*)&shp[kk + 4];
            x0 = affine4(x0, sc0, sh0); x1 = affine4(x1, sc1, sh1);
            y0 = affine4(y0, sc0, sh0); y1 = affine4(y1, sc1, sh1);
            if (ok0) {
                *(float4*)&Hw[(size_t)ar0 * ldh + kk] = x0;
                *(float4*)&Hw[(size_t)ar0 * ldh + kk + 4] = x1;
            }
            if (ok1) {
                *(float4*)&Hw[(size_t)ar1 * ldh + kk] = y0;
                *(float4*)&Hw[(size_t)ar1 * ldh + kk + 4] = y1;
            }
        }
        union { unsigned int u[4]; bf16x8 v; } af0, af1;
        af0.u[0] = pack2bf(x0.x, x0.y); af0.u[1] = pack2bf(x0.z, x0.w);
        af0.u[2] = pack2bf(x1.x, x1.y); af0.u[3] = pack2bf(x1.z, x1.w);
        af1.u[0] = pack2bf(y0.x, y0.y); af1.u[1] = pack2bf(y0.z, y0.w);
        af1.u[2] = pack2bf(y1.x, y1.y); af1.u[3] = pack2bf(y1.z, y1.w);
#pragma unroll
        for (int ct = 0; ct < 8; ct++) {
            bf16x8 b = *(const bf16x8*)&Bt[ct * 16 + l15][lhi * 4];
            acc[0][ct] = __builtin_amdgcn_mfma_f32_16x16x32_bf16(af0.v, b, acc[0][ct], 0, 0, 0);
            acc[1][ct] = __builtin_amdgcn_mfma_f32_16x16x32_bf16(af1.v, b, acc[1][ct], 0, 0, 0);
        }
    }
#pragma unroll
    for (int rt = 0; rt < 2; rt++)
#pragma unroll
        for (int ct = 0; ct < 8; ct++)
#pragma unroll
            for (int reg = 0; reg < 4; reg++) {
                int row = rowbase + rt * 16 + lhi * 4 + reg;
                if (row < NN)
                    out[(size_t)row * NH + ct * 16 + l15] = __float2bfloat16(acc[rt][ct][reg]);
            }
}

// ---------------- plain GEMM (layer 1) ----------------
__global__ __launch_bounds__(256) void k_gemm1(const float* __restrict__ H,
                                               const float* __restrict__ W,
                                               __hip_bfloat16* __restrict__ out) {
    __shared__ unsigned int Bt[128][20];
    gemm_body<NF, false>(Bt, H, nullptr, nullptr, nullptr, NF, W, out, (int)blockIdx.x, (int)threadIdx.x);
}

// ---------------- BN-fused GEMM for layers 2/3: scale/shift computed per block from raw sums ----------------
__global__ __launch_bounds__(256) void k_gemm_bn(const float* H, float* Hw,
                                                 const float* __restrict__ sums,
                                                 const float* __restrict__ g,
                                                 const float* __restrict__ beta,
                                                 const float* __restrict__ W,
                                                 __hip_bfloat16* __restrict__ out) {
    __shared__ unsigned int Bt[128][20];
    __shared__ __align__(16) float scL[128];
    __shared__ __align__(16) float shL[128];
    int t = threadIdx.x;
    if (t < 128) {
        float m = sums[t] * (1.0f / NN);
        float v = sums[NH + t] * (1.0f / NN) - m * m;
        float r = rsqrtf(v + BN_EPS);
        float sc = g[t] * r;
        scL[t] = sc;
        shL[t] = beta[t] - m * sc;
    }
    __syncthreads();
    gemm_body<NH, true>(Bt, H, Hw, scL, shL, 384, W, out, (int)blockIdx.x, (int)threadIdx.x);
}

// ---------------- CSR gather-aggregate (bf16 lin), full-row, 16-deep pipeline, 4 nodes/block ----------------
// Deliberately minimal: VGPR 12, no LDS, no barriers (R14: appended work costs 3x its savings).
__global__ __launch_bounds__(256) void k_agg(const unsigned int* __restrict__ linb,
                                             const float* __restrict__ dinv,
                                             const int* __restrict__ rowptr,
                                             const unsigned int* __restrict__ cw,
                                             const float* __restrict__ bias,
                                             float* __restrict__ outp, int do_relu) {
    int t = threadIdx.x;
    int node = blockIdx.x * 4 + (t >> 6);
    if (node >= NN) return;
    int ch = t & 63;
    int c = ch << 1;
    float di = dinv[node];
    float2 sv = bf2_unpack(linb[(size_t)node * 64 + ch]);
    float a0 = fmaf(sv.x, di * di, bias[c]);
    float a1 = fmaf(sv.y, di * di, bias[c + 1]);
    int beg = rowptr[node], end = rowptr[node + 1];
    int j = beg;
    for (; j + 16 <= end; j += 16) {
        unsigned int pk[16];
#pragma unroll
        for (int q = 0; q < 16; q++) pk[q] = cw[j + q];
        unsigned int v[16];
#pragma unroll
        for (int q = 0; q < 16; q++) v[q] = linb[(size_t)(pk[q] & 0x1FFFFu) * 64 + ch];
#pragma unroll
        for (int q = 0; q < 16; q++) {
            float w = __half2float(__ushort_as_half((unsigned short)(pk[q] >> 17)));
            float2 f = bf2_unpack(v[q]);
            a0 = fmaf(f.x, w, a0);
            a1 = fmaf(f.y, w, a1);
        }
    }
    for (; j + 4 <= end; j += 4) {
        unsigned int pk[4];
#pragma unroll
        for (int q = 0; q < 4; q++) pk[q] = cw[j + q];
        unsigned int v[4];
#pragma unroll
        for (int q = 0; q < 4; q++) v[q] = linb[(size_t)(pk[q] & 0x1FFFFu) * 64 + ch];
#pragma unroll
        for (int q = 0; q < 4; q++) {
            float w = __half2float(__ushort_as_half((unsigned short)(pk[q] >> 17)));
            float2 f = bf2_unpack(v[q]);
            a0 = fmaf(f.x, w, a0);
            a1 = fmaf(f.y, w, a1);
        }
    }
    for (; j < end; j++) {
        unsigned int pk = cw[j];
        unsigned int vv = linb[(size_t)(pk & 0x1FFFFu) * 64 + ch];
        float w = __half2float(__ushort_as_half((unsigned short)(pk >> 17)));
        float2 f = bf2_unpack(vv);
        a0 = fmaf(f.x, w, a0);
        a1 = fmaf(f.y, w, a1);
    }
    if (do_relu) { a0 = fmaxf(a0, 0.f); a1 = fmaxf(a1, 0.f); }
    *(float2*)&outp[(size_t)node * 384 + c] = make_float2(a0, a1);
}

// ---------------- BN stats (R13 version) ----------------
__global__ __launch_bounds__(256) void k_stats(const float* __restrict__ pre, float* __restrict__ sums) {
    int t = threadIdx.x;
    int c = t & 127, h = t >> 7;
    float s = 0.f, s2 = 0.f;
    for (int r = blockIdx.x * 2 + h; r < NN; r += gridDim.x * 2) {
        float v = pre[(size_t)r * 384 + c];
        s += v;
        s2 = fmaf(v, v, s2);
    }
    __shared__ float ls[256], ls2[256];
    ls[t] = s; ls2[t] = s2;
    __syncthreads();
    if (t < 128) {
        atomicAdd(&sums[c], ls[t] + ls[t + 128]);
        atomicAdd(&sums[NH + c], ls2[t] + ls2[t + 128]);
    }
}

// ---------------- final linear [NN,384]@[384,40] via MFMA + softmax; BN3 computed in-block ----------------
// Normalized x3 written back only for unclamped rows (clamped duplicates would race).
__global__ __launch_bounds__(256) void k_final(const float* __restrict__ embed, float* embedW,
                                               const float* __restrict__ sums3,
                                               const float* __restrict__ g3,
                                               const float* __restrict__ be3,
                                               const float* __restrict__ linW,
                                               const float* __restrict__ linb,
                                               float* __restrict__ logits, float* __restrict__ probs) {
    __shared__ unsigned int Wt[3 * 16 * 196];  // 37632 B
    __shared__ __align__(16) float scL[128];
    __shared__ __align__(16) float shL[128];
    int t = threadIdx.x;
    if (t < 128) {
        float m = sums3[t] * (1.0f / NN);
        float v = sums3[NH + t] * (1.0f / NN) - m * m;
        float r = rsqrtf(v + BN_EPS);
        float sc = g3[t] * r;
        scL[t] = sc;
        shL[t] = be3[t] - m * sc;
    }
    for (int i = t; i < 3 * 16 * 192; i += 256) {
        int ct = i / (16 * 192);
        int rem = i - ct * (16 * 192);
        int c = rem / 192, k2 = rem - c * 192;
        int col = ct * 16 + c;
        float lo = (col < NC) ? linW[(size_t)(2 * k2) * NC + col] : 0.f;
        float hi = (col < NC) ? linW[(size_t)(2 * k2 + 1) * NC + col] : 0.f;
        Wt[(ct * 16 + c) * 196 + k2] = pack2bf(lo, hi);
    }
    __syncthreads();

    int wid = t >> 6, l = t & 63;
    int rowbase = blockIdx.x * 64 + wid * 16;
    int l15 = l & 15, lhi = l >> 4;

    bool okA = (rowbase + l15) < NN;
    int arow = rowbase + l15;
    if (arow > NN - 1) arow = NN - 1;
    const float4* ap = (const float4*)&embed[(size_t)arow * 384 + lhi * 8];

    f32x4 acc0 = {0.f, 0.f, 0.f, 0.f};
    f32x4 acc1 = {0.f, 0.f, 0.f, 0.f};
    f32x4 acc2 = {0.f, 0.f, 0.f, 0.f};

    for (int kb = 0; kb < 12; kb++) {
        float4 a0 = ap[kb * 8];
        float4 a1 = ap[kb * 8 + 1];
        if (kb >= 8) {  // x3 columns: apply BN3 affine, write normalized back (owners only)
            int kk = kb * 32 + lhi * 8 - 256;
            float4 sc0 = *(const float4*)&scL[kk];
            float4 sc1 = *(const float4*)&scL[kk + 4];
            float4 sh0 = *(const float4*)&shL[kk];
            float4 sh1 = *(const float4*)&shL[kk + 4];
            a0 = affine4(a0, sc0, sh0);
            a1 = affine4(a1, sc1, sh1);
            if (okA) {
                *(float4*)&embedW[(size_t)arow * 384 + kb * 32 + lhi * 8] = a0;
                *(float4*)&embedW[(size_t)arow * 384 + kb * 32 + lhi * 8 + 4] = a1;
            }
        }
        union { unsigned int u[4]; bf16x8 v; } af;
        af.u[0] = pack2bf(a0.x, a0.y);
        af.u[1] = pack2bf(a0.z, a0.w);
        af.u[2] = pack2bf(a1.x, a1.y);
        af.u[3] = pack2bf(a1.z, a1.w);
        int wbase = kb * 16 + lhi * 4;
        bf16x8 b0 = *(const bf16x8*)&Wt[(0 * 16 + l15) * 196 + wbase];
        bf16x8 b1 = *(const bf16x8*)&Wt[(1 * 16 + l15) * 196 + wbase];
        bf16x8 b2 = *(const bf16x8*)&Wt[(2 * 16 + l15) * 196 + wbase];
        acc0 = __builtin_amdgcn_mfma_f32_16x16x32_bf16(af.v, b0, acc0, 0, 0, 0);
        acc1 = __builtin_amdgcn_mfma_f32_16x16x32_bf16(af.v, b1, acc1, 0, 0, 0);
        acc2 = __builtin_amdgcn_mfma_f32_16x16x32_bf16(af.v, b2, acc2, 0, 0, 0);
    }

    int col0 = 0 * 16 + l15, col1 = 1 * 16 + l15, col2 = 2 * 16 + l15;
    float lb0 = (col0 < NC) ? linb[col0] : 0.f;
    float lb1 = (col1 < NC) ? linb[col1] : 0.f;
    float lb2 = (col2 < NC) ? linb[col2] : 0.f;

#pragma unroll
    for (int reg = 0; reg < 4; reg++) {
        int row = rowbase + lhi * 4 + reg;
        float v0 = acc0[reg] + lb0;
        float v1 = acc1[reg] + lb1;
        float v2 = acc2[reg] + lb2;
        float m = fmaxf(v0, v1);
        if (col2 < NC) m = fmaxf(m, v2);
#pragma unroll
        for (int off = 1; off < 16; off <<= 1) m = fmaxf(m, __shfl_xor(m, off));
        float e0 = __expf(v0 - m);
        float e1 = __expf(v1 - m);
        float e2 = (col2 < NC) ? __expf(v2 - m) : 0.f;
        float s = e0 + e1 + e2;
#pragma unroll
        for (int off = 1; off < 16; off <<= 1) s += __shfl_xor(s, off);
        float inv = 1.0f / s;
        if (row < NN) {
            size_t base = (size_t)row * NC;
            logits[base + col0] = v0;
            probs[base + col0] = e0 * inv;
            logits[base + col1] = v1;
            probs[base + col1] = e1 * inv;
            if (col2 < NC) {
                logits[base + col2] = v2;
                probs[base + col2] = e2 * inv;
            }
        }
    }
}

extern "C" void kernel_launch(void* const* d_in, const int* in_sizes, int n_in,
                              void* d_out, int out_size, void* d_ws, size_t ws_size,
                              hipStream_t stream) {
    const float* x    = (const float*)d_in[0];
    const int*   ei   = (const int*)d_in[1];
    const float* ew   = (const float*)d_in[2];
    const float* W1   = (const float*)d_in[3];
    const float* b1   = (const float*)d_in[4];
    const float* g1   = (const float*)d_in[5];
    const float* be1  = (const float*)d_in[6];
    const float* W2   = (const float*)d_in[7];
    const float* b2   = (const float*)d_in[8];
    const float* g2   = (const float*)d_in[9];
    const float* be2  = (const float*)d_in[10];
    const float* W3   = (const float*)d_in[11];
    const float* b3   = (const float*)d_in[12];
    const float* g3   = (const float*)d_in[13];
    const float* be3  = (const float*)d_in[14];
    const float* linW = (const float*)d_in[15];
    const float* linb = (const float*)d_in[16];

    float* out    = (float*)d_out;
    float* logits = out;
    float* probs  = out + (size_t)NN * NC;
    float* embed  = out + (size_t)2 * NN * NC;

    char* ws = (char*)d_ws;
    size_t off = 0;
    auto alloc = [&](size_t bytes) -> char* {
        char* p = ws + off;
        off = (off + bytes + 255) & ~(size_t)255;
        return p;
    };
    float*              dinv    = (float*)alloc((size_t)NN * 4);
    unsigned long long* hist    = (unsigned long long*)alloc((size_t)NN * 8);
    int*                rowptr  = (int*)alloc((size_t)(NN + 1) * 4);
    int*                partial = (int*)alloc(128 * 4);
    unsigned int*       cw      = (unsigned int*)alloc((size_t)NE * 4);
    __hip_bfloat16*     lin     = (__hip_bfloat16*)alloc((size_t)NN * NH * 2);
    unsigned int*       pos     = (unsigned int*)alloc((size_t)NE * 4);
    float*              sums    = (float*)alloc(3 * 1024 * 4);
    (void)ws_size; (void)in_sizes; (void)n_in; (void)out_size;

    int gN = (NN + 255) / 256;
    int gE = (NE + 255) / 256;
    int gM = (NN + 127) / 128;
    int gA = (NN + 3) / 4;
    int gF = (NN + 63) / 64;

    k_init<<<gN, 256, 0, stream>>>(hist, sums);
    k_edge<<<gE, 256, 0, stream>>>(ei, ew, hist, pos);
    k_scanA<<<NB, 256, 0, stream>>>(hist, partial, dinv);
    k_scanB<<<1, 128, 0, stream>>>(partial, rowptr);
    k_scanC<<<NB, 256, 0, stream>>>(hist, partial, rowptr);
    k_scatter<<<gE, 256, 0, stream>>>(ei, dinv, rowptr, pos, cw);

    // layer 1
    k_gemm1<<<gM, 256, 0, stream>>>(x, W1, lin);
    k_agg<<<gA, 256, 0, stream>>>((const unsigned int*)lin, dinv, rowptr, cw, b1, embed + 0, 1);
    k_stats<<<1024, 256, 0, stream>>>(embed + 0, sums + 0);
    // layer 2: GEMM computes BN1 scale/shift in-block, normalizes x1, writes back + lin2
    k_gemm_bn<<<gM, 256, 0, stream>>>(embed + 0, embed + 0, sums + 0, g1, be1, W2, lin);
    k_agg<<<gA, 256, 0, stream>>>((const unsigned int*)lin, dinv, rowptr, cw, b2, embed + 128, 1);
    k_stats<<<1024, 256, 0, stream>>>(embed + 128, sums + 1024);
    // layer 3
    k_gemm_bn<<<gM, 256, 0, stream>>>(embed + 128, embed + 128, sums + 1024, g2, be2, W3, lin);
    k_agg<<<gA, 256, 0, stream>>>((const unsigned int*)lin, dinv, rowptr, cw, b3, embed + 256, 0);
    k_stats<<<1024, 256, 0, stream>>>(embed + 256, sums + 2048);
    // final linear + softmax; BN3 computed in-block, normalized x3 written back
    k_final<<<gF, 256, 0, stream>>>(embed, embed, sums + 2048, g3, be3, linW, linb, logits, probs);
}